// Round 8
// baseline (494.306 us; speedup 1.0000x reference)
//
#include <hip/hip_runtime.h>
#include <math.h>

// Problem constants
#define BB   128
#define LL   512
#define CC   321
#define PREDD 336
// Seasonal MLP: rows = B*C*S = 164352, dims 128 -> 512 -> 128 (x2 blocks)

using bf16x8  = __attribute__((ext_vector_type(8))) __bf16;
using floatx4 = __attribute__((ext_vector_type(4))) float;
using uintx4  = __attribute__((ext_vector_type(4))) unsigned int;
typedef unsigned short u16;
typedef unsigned int u32;

#define MFMA16(a,b,c) __builtin_amdgcn_mfma_f32_16x16x32_bf16(a,b,c,0,0,0)

__device__ __forceinline__ u16 f2bf(float f){
    union { float f; unsigned u; } v; v.f = f;
    unsigned r = v.u + 0x7FFFu + ((v.u >> 16) & 1u);   // RNE
    return (u16)(r >> 16);
}

// packed f32x2 -> bf16x2 (RNE), 1 instr / 2 elements
__device__ __forceinline__ u32 cvtpk(float a, float b){
    u32 r;
    asm("v_cvt_pk_bf16_f32 %0, %1, %2" : "=v"(r) : "v"(a), "v"(b));
    return r;
}

// tanh-GELU via exp2: max |err| vs exact erf-GELU ~3e-4 << bf16 rounding.
// R6 evidence: per-element form beats batched-rcp (latency-chain bound kernel).
__device__ __forceinline__ float fgelu(float x){
    float u = x*(0.7978845608f + 0.035677408f*x*x);
    float a = fminf(u*2.8853900818f, 80.f);       // 2*log2(e)*u, clamp vs inf/inf
    float t = __builtin_amdgcn_exp2f(a);          // v_exp_f32
    return x*t*__builtin_amdgcn_rcpf(1.f + t);
}

// XOR-segment swizzle (16B segs): s' = (s&8)|((s^r)&7) -- self-inverse.
__device__ __forceinline__ int swz64 (int r, int s){ return r*64  + (((s ^ r) & 7) << 3); }

// async global->LDS DMA, 16B per lane; LDS dest = uniform base + lane*16.
__device__ __forceinline__ void dma16(const u16* g, const u16* l){
    __builtin_amdgcn_global_load_lds(
        (const __attribute__((address_space(1))) u32*)g,
        (__attribute__((address_space(3))) u32*)l, 16, 0, 0);
}

// ---------------- merged prep + decomp ----------------------------------------------------
// Blocks [0,2688): fused RevIN stats + moving-avg decomposition (R7 body, XCD-remapped).
// Blocks [2688,4224): weight prep fp32->bf16 pre-transposed (R1/R7 body).
// Merging removes one launch gap and overlaps prep's ~10us with decomp's memory phase.
#define XT(t,c) xt[((t)<<4) + (((t)>>5)<<1) + (c)]
__global__ __launch_bounds__(256) void dp_k(
    const float* __restrict__ x, const float* __restrict__ rw, const float* __restrict__ rb,
    u16* __restrict__ Afin, u16* __restrict__ xs, float2* __restrict__ stats,
    const float* __restrict__ W11, const float* __restrict__ W12,
    const float* __restrict__ W21, const float* __restrict__ W22,
    const float* __restrict__ Wtr, const float* __restrict__ Wse,
    u16* __restrict__ BT1, u16* __restrict__ BT2,
    u16* __restrict__ BT3, u16* __restrict__ BT4,
    u16* __restrict__ BT5)
{
    if (blockIdx.x >= 2688){
        // ---- prep body ----
        int idx = (blockIdx.x - 2688) * 256 + threadIdx.x;
        if (idx < 65536){
            int h = idx >> 7;                      // BT1/BT3: [512][128] = W11^T / W21^T (sigma rows)
            int k = idx & 127;
            int hp = (h & ~31) | (((h >> 2) & 3)*8 + ((h >> 4) & 1)*4 + (h & 3));
            BT1[idx] = f2bf(W11[k*512 + hp]);
            BT3[idx] = f2bf(W21[k*512 + hp]);
            int n = idx >> 9, k2 = idx & 511;      // BT2/BT4: [128][512] = W12^T / W22^T
            int np = ((n >> 5) & 3)*32 + ((n >> 2) & 3)*8 + ((n >> 4) & 1)*4 + (n & 3);
            BT2[idx] = f2bf(W12[k2*128 + np]);     // rows n~-permuted
            BT4[idx] = f2bf(W22[k2*128 + n]);      // identity
        }
        if (idx < 393216){
            // BT5: [384][1024]; k<512 -> W_tr rows; k>=512 -> W_se rows permuted to (s,n)-major
            int p = idx >> 10, k = idx & 1023;
            float v = 0.f;
            if (p < PREDD){
                if (k < 512) v = Wtr[k*PREDD + p];
                else { int kk = k - 512; int s = kk >> 7; int n = kk & 127; v = Wse[(4*n + s)*PREDD + p]; }
            }
            BT5[idx] = f2bf(v);
        }
        return;
    }

    // ---- decomp body ----
    __shared__ float xt[8240];
    __shared__ float red[2][16][16];
    __shared__ float sh_m[16], sh_istd[16];
    int b = blockIdx.x & 127, ct = blockIdx.x >> 7;   // XCD co-location remap
    int tid = threadIdx.x;

    int cl = tid & 15, lp = tid >> 4;
    int c = ct*16 + cl;
    bool valid = c < CC;
    const float* xb = x + (size_t)b*LL*CC;
    float s = 0.f, q = 0.f;
    for (int i = 0; i < 32; ++i){
        int t = lp + 16*i;
        float v = valid ? xb[(size_t)t*CC + c] : 0.f;
        XT(t, cl) = v;
        s += v; q += v*v;
    }
    red[0][lp][cl] = s; red[1][lp][cl] = q;
    __syncthreads();
    if (tid < 16){
        float ss = 0.f, qq = 0.f;
        for (int j = 0; j < 16; ++j){ ss += red[0][j][tid]; qq += red[1][j][tid]; }
        float m  = ss * (1.f/512.f);
        float var = qq * (1.f/512.f) - m*m;
        float sd = sqrtf(var + 1e-5f);
        sh_m[tid] = m; sh_istd[tid] = 1.f/sd;
        int cc = ct*16 + tid;
        if (cc < CC) stats[(size_t)b*CC + cc] = make_float2(m, sd);
    }
    __syncthreads();

    int ch = tid >> 4, tp = tid & 15;
    int c2 = ct*16 + ch;
    if (c2 >= CC) return;
    float m = sh_m[ch], istd = sh_istd[ch];
    float w = rw[c2] * istd, bbv = rb[c2];
    size_t bc = (size_t)b*CC + c2;
    u16* tr  = Afin + bc*1024;
    u16* xsr = xs   + bc*512;
    int t0 = tp*32;

    float win = 0.f;
#pragma unroll
    for (int d = -12; d <= 12; ++d){
        int u = t0 + d; u = u < 0 ? 0 : (u > 511 ? 511 : u);
        win += XT(u, ch);
    }
    u16 trbuf[8];
    u16 xsbuf[4][8];
#pragma unroll
    for (int i = 0; i < 32; ++i){
        int t = t0 + i;
        float Ax = win * (1.f/25.f);
        float xv = XT(t, ch);
        trbuf[i & 7] = f2bf((Ax - m)*w + bbv);
        xsbuf[i & 3][i >> 2] = f2bf((xv - Ax)*w);
        if ((i & 7) == 7)
            *(uintx4*)(tr + t0 + (i & ~7)) = *(const uintx4*)trbuf;
        int uo = t - 12; uo = uo < 0 ? 0 : uo;
        int un = t + 13; un = un > 511 ? 511 : un;
        win += XT(un, ch) - XT(uo, ch);
    }
#pragma unroll
    for (int s4 = 0; s4 < 4; ++s4)
        *(uintx4*)(xsr + s4*128 + tp*8) = *(const uintx4*)xsbuf[s4];
}

// ---------------- fused 2-block MLP (R7 body; R8 delta: 4 blocks/CU) ----------------------
// Latency-bound (MfmaUtil 24 / VALU 52 / Occ 24, nothing saturated): add TLP.
// 4 blocks x 32KB LDS = 128KB <= 160KB; VGPR 80 <= 128 cap at 4 waves/EU.
__global__ __launch_bounds__(256, 4) void mlp_fused_k(
    const u16* __restrict__ xs,
    const u16* __restrict__ BT1, const float* __restrict__ b11,
    const u16* __restrict__ BT2, const float* __restrict__ b12,
    const u16* __restrict__ BT3, const float* __restrict__ b21,
    const u16* __restrict__ BT4, const float* __restrict__ b22,
    u16* __restrict__ Afin)
{
    __shared__ u16 lds[16384];   // 32 KB: slot g&1: [0,4096) W1c[32][128]swz128, [4096,8192) W2c[128][32]swz
    const int tid  = threadIdx.x;
    const int lane = tid & 63;
    const int wv   = tid >> 6;
    const int quad = lane >> 4, cl = lane & 15;
    const int wrow = blockIdx.x * 128 + wv*32;       // wave's 32 rows

    // per-thread DMA offsets (constant across g)
    const int qq0 = tid, qq1 = tid + 256;
    const int rA0 = qq0 >> 4, spA0 = qq0 & 15;
    const int rA1 = qq1 >> 4, spA1 = qq1 & 15;
    const int offA0 = rA0*128 + (((spA0 & 8) | ((spA0 ^ rA0) & 7)) << 3);
    const int offA1 = rA1*128 + (((spA1 & 8) | ((spA1 ^ rA1) & 7)) << 3);
    const int rB0 = qq0 >> 2, spB0 = qq0 & 3;
    const int rB1 = qq1 >> 2, spB1 = qq1 & 3;
    const int offB0 = rB0*512 + ((spB0 ^ ((rB0 >> 1) & 3)) << 3);
    const int offB1 = rB1*512 + ((spB1 ^ ((rB1 >> 1) & 3)) << 3);

#define STAGE(dst, w1src, w2src, G)                                          \
    dma16((w1src) + (G)*4096 + offA0, lds + (dst) + qq0*8);                  \
    dma16((w1src) + (G)*4096 + offA1, lds + (dst) + qq1*8);                  \
    dma16((w2src) + (G)*32  + offB0, lds + (dst) + 4096 + qq0*8);            \
    dma16((w2src) + (G)*32  + offB1, lds + (dst) + 4096 + qq1*8);

    // chunk 0 -> slot 0
    STAGE(0, BT1, BT2, 0)

    // x fragments from global (L2/L3-warm from decomp); GEMM1 B-operand. Once per wave.
    bf16x8 xfrag[2][4];
#pragma unroll
    for (int mt = 0; mt < 2; ++mt)
#pragma unroll
        for (int ks = 0; ks < 4; ++ks)
            xfrag[mt][ks] = *(const bf16x8*)(xs + (size_t)(wrow + mt*16 + cl)*128 + ks*32 + quad*8);

    floatx4 Yacc[16];
#pragma unroll
    for (int i = 0; i < 16; ++i) Yacc[i] = (floatx4){0.f,0.f,0.f,0.f};

    __syncthreads();                                 // chunk 0 landed

    const int w2rd = (quad ^ ((cl >> 1) & 3)) << 3;  // W2c read seg offset (u16)

    for (int g = 0; g < 32; ++g){
        const int cur = (g & 1) ? 8192 : 0;
        if (g < 31){                                 // DMA chunk g+1 (lands during this chunk)
            const int nxt = 8192 - cur;
            const u16* w1s = ((g+1) & 16) ? BT3 : BT1;
            const u16* w2s = ((g+1) & 16) ? BT4 : BT2;
            const int hn = (g+1) & 15;
            STAGE(nxt, w1s, w2s, hn)
        }
        const float* ba = (g & 16) ? b21 : b11;
        const int hc = g & 15;

        // GEMM1: hacc[f][mt] = W1c x xfrag  (Ht tiles; h-slot = 4*quad+i, m = cl)
        floatx4 hacc[2][2];
        hacc[0][0] = hacc[0][1] = hacc[1][0] = hacc[1][1] = (floatx4){0.f,0.f,0.f,0.f};
#pragma unroll
        for (int ks = 0; ks < 4; ++ks){
            const int sg = ks*4 + quad;
            const int s0 = ((sg & 8) | ((sg ^ cl) & 7)) << 3;
            bf16x8 wf0 = *(const bf16x8*)(lds + cur + cl*128 + s0);
            bf16x8 wf1 = *(const bf16x8*)(lds + cur + (16 + cl)*128 + s0);
#pragma unroll
            for (int mt = 0; mt < 2; ++mt){
                hacc[0][mt] = MFMA16(wf0, xfrag[mt][ks], hacc[0][mt]);
                hacc[1][mt] = MFMA16(wf1, xfrag[mt][ks], hacc[1][mt]);
            }
        }

        // bias + GELU + pack: lane's 8 values ARE its B-fragment (sigma permutation)
        const float4 bA = *(const float4*)(ba + hc*32 + quad*8);
        const float4 bB = *(const float4*)(ba + hc*32 + quad*8 + 4);
        bf16x8 a2[2];
#pragma unroll
        for (int mt = 0; mt < 2; ++mt){
            union { bf16x8 v; u32 w[4]; } u;
            u.w[0] = cvtpk(fgelu(hacc[0][mt][0] + bA.x), fgelu(hacc[0][mt][1] + bA.y));
            u.w[1] = cvtpk(fgelu(hacc[0][mt][2] + bA.z), fgelu(hacc[0][mt][3] + bA.w));
            u.w[2] = cvtpk(fgelu(hacc[1][mt][0] + bB.x), fgelu(hacc[1][mt][1] + bB.y));
            u.w[3] = cvtpk(fgelu(hacc[1][mt][2] + bB.z), fgelu(hacc[1][mt][3] + bB.w));
            a2[mt] = u.v;
        }

        // GEMM2: Yacc (Y^T) += W2c x a2   (n-slot tiles nt2, m = cl)
#pragma unroll
        for (int nt2 = 0; nt2 < 8; ++nt2){
            bf16x8 b2 = *(const bf16x8*)(lds + cur + 4096 + (nt2*16 + cl)*32 + w2rd);
#pragma unroll
            for (int mt = 0; mt < 2; ++mt)
                Yacc[mt*8 + nt2] = MFMA16(b2, a2[mt], Yacc[mt*8 + nt2]);
        }
        __syncthreads();                             // slot reads done + DMA g+1 drained

        if (g == 15){
            // mlp0 -> mlp1 handoff: h1 = Y + b12, register-only (n~ permutation)
#pragma unroll
            for (int ks = 0; ks < 4; ++ks){
                const float4 cA = *(const float4*)(b12 + ks*32 + quad*8);
                const float4 cB = *(const float4*)(b12 + ks*32 + quad*8 + 4);
#pragma unroll
                for (int mt = 0; mt < 2; ++mt){
                    floatx4 y0 = Yacc[mt*8 + 2*ks];
                    floatx4 y1 = Yacc[mt*8 + 2*ks + 1];
                    union { bf16x8 v; u32 w[4]; } u;
                    u.w[0] = cvtpk(y0[0] + cA.x, y0[1] + cA.y);
                    u.w[1] = cvtpk(y0[2] + cA.z, y0[3] + cA.w);
                    u.w[2] = cvtpk(y1[0] + cB.x, y1[1] + cB.y);
                    u.w[3] = cvtpk(y1[2] + cB.z, y1[3] + cB.w);
                    xfrag[mt][ks] = u.v;
                }
            }
#pragma unroll
            for (int i = 0; i < 16; ++i) Yacc[i] = (floatx4){0.f,0.f,0.f,0.f};
        }
    }
#undef STAGE

    // epilogue: h2 + b22 -> Afin[:, 512 + s*128 + n]; 8B packed stores
#pragma unroll
    for (int mt = 0; mt < 2; ++mt){
        const int gr = wrow + mt*16 + cl;
        u16* dst = Afin + (size_t)(gr >> 2)*1024 + 512 + (size_t)(gr & 3)*128 + quad*4;
#pragma unroll
        for (int nt2 = 0; nt2 < 8; ++nt2){
            const float4 cB = *(const float4*)(b22 + nt2*16 + quad*4);
            floatx4 v = Yacc[mt*8 + nt2];
            union { unsigned long long d; u32 w[2]; } u;
            u.w[0] = cvtpk(v[0] + cB.x, v[1] + cB.y);
            u.w[1] = cvtpk(v[2] + cB.z, v[3] + cB.w);
            *(unsigned long long*)(dst + nt2*16) = u.d;
        }
    }
}

// ---------------- final fused-head GEMM, DMA double-buffered, XCD-grouped (unchanged) -----
__global__ __launch_bounds__(256, 2) void head_gemm_k(
    const u16* __restrict__ A, const u16* __restrict__ BT,
    float* __restrict__ Cf,
    const float* __restrict__ bias, const float* __restrict__ bias2,
    const float* __restrict__ rw, const float* __restrict__ rb,
    const float2* __restrict__ stats)
{
    __shared__ u16 lds[32768];    // A slices @0,@8192 ; B slices @16384,@24576
    const int id = blockIdx.x;
    const int xcd = id & 7, slot = id >> 3;
    const int g8 = slot / 3, j = slot - g8*3;
    const int by = xcd + 8*g8;
    if (by >= 321) return;
    const int row0 = by * 128, col0 = j * 128;

    const int tid = threadIdx.x;
    const int lane = tid & 63;
    const int wv = tid >> 6;
    const int wm = wv & 1, wn = wv >> 1;
    const int quad = lane >> 4, cl = lane & 15;

    const int qbase = wv*4*64 + lane;

#pragma unroll
    for (int i = 0; i < 4; ++i){
        int qq = qbase + i*64;
        int r = qq >> 3, p = qq & 7; int s = (p ^ r) & 7;
        dma16(A  + (size_t)(row0 + r)*1024 + s*8, lds + qq*8);
        dma16(BT + (size_t)(col0 + r)*1024 + s*8, lds + 16384 + qq*8);
    }
    __syncthreads();

    floatx4 acc[16];
#pragma unroll
    for (int i = 0; i < 16; ++i) acc[i] = (floatx4){0.f,0.f,0.f,0.f};

    for (int it = 0; it < 16; ++it){
        const int cur = (it & 1) * 8192;
        if (it < 15){
            const int nxt = ((it+1) & 1) * 8192;
            const int k0 = (it+1) * 64;
#pragma unroll
            for (int i = 0; i < 4; ++i){
                int qq = qbase + i*64;
                int r = qq >> 3, p = qq & 7; int s = (p ^ r) & 7;
                dma16(A  + (size_t)(row0 + r)*1024 + k0 + s*8, lds + nxt + qq*8);
                dma16(BT + (size_t)(col0 + r)*1024 + k0 + s*8, lds + 16384 + nxt + qq*8);
            }
        }
#pragma unroll
        for (int kk = 0; kk < 2; ++kk){
            bf16x8 af[4], bfr[4];
#pragma unroll
            for (int mt = 0; mt < 4; ++mt) af[mt]  = *(const bf16x8*)(lds + cur + swz64(wm*64 + mt*16 + cl, kk*4 + quad));
#pragma unroll
            for (int nt = 0; nt < 4; ++nt) bfr[nt] = *(const bf16x8*)(lds + 16384 + cur + swz64(wn*64 + nt*16 + cl, kk*4 + quad));
#pragma unroll
            for (int mt = 0; mt < 4; ++mt)
#pragma unroll
                for (int nt = 0; nt < 4; ++nt)
                    acc[mt*4+nt] = MFMA16(af[mt], bfr[nt], acc[mt*4+nt]);
        }
        __syncthreads();
    }

#pragma unroll
    for (int mt = 0; mt < 4; ++mt)
#pragma unroll
        for (int nt = 0; nt < 4; ++nt){
            floatx4 v = acc[mt*4+nt];
            int gc = col0 + wn*64 + nt*16 + cl;
            if (gc >= PREDD) continue;
            float bsum = bias[gc] + bias2[gc];
#pragma unroll
            for (int i = 0; i < 4; ++i){
                int gr = row0 + wm*64 + mt*16 + quad*4 + i;
                float val = v[i] + bsum;
                int bv2 = gr / CC;
                int c  = gr - bv2*CC;
                val = (val - rb[c]) / (rw[c] + 1e-10f);
                float2 st = stats[gr];
                val = val*st.y + st.x;
                Cf[(size_t)bv2*(PREDD*CC) + (size_t)gc*CC + c] = val;
            }
        }
}

extern "C" void kernel_launch(void* const* d_in, const int* in_sizes, int n_in,
                              void* d_out, int out_size, void* d_ws, size_t ws_size,
                              hipStream_t stream)
{
    const float* x   = (const float*)d_in[0];
    const float* rvw = (const float*)d_in[1];
    const float* rvb = (const float*)d_in[2];
    const float* W11 = (const float*)d_in[3];
    const float* b11 = (const float*)d_in[4];
    const float* W12 = (const float*)d_in[5];
    const float* b12 = (const float*)d_in[6];
    const float* W21 = (const float*)d_in[7];
    const float* b21 = (const float*)d_in[8];
    const float* W22 = (const float*)d_in[9];
    const float* b22 = (const float*)d_in[10];
    const float* Wtr = (const float*)d_in[11];
    const float* btr = (const float*)d_in[12];
    const float* Wse = (const float*)d_in[13];
    const float* bse = (const float*)d_in[14];
    float* out = (float*)d_out;

    char* ws = (char*)d_ws;
    u16* BT1 = (u16*)(ws + 0);            //  512x128 bf16 (sigma-permuted rows)
    u16* BT2 = (u16*)(ws + 131072);       //  128x512 (n~-permuted rows)
    u16* BT3 = (u16*)(ws + 262144);       //  512x128 (sigma-permuted rows)
    u16* BT4 = (u16*)(ws + 393216);       //  128x512 (identity)
    u16* BT5 = (u16*)(ws + 524288);       //  384x1024
    float2* stats = (float2*)(ws + 1310720);      // 41088 x {mean,std}
    u16* Afin = (u16*)(ws + 1639424);     // concat-A [41088][1024]: trend | sea
    u16* xs   = (u16*)(ws + 85787648);    // [164352][128] split seasonal

    hipLaunchKernelGGL(dp_k, dim3(4224), dim3(256), 0, stream,
                       x, rvw, rvb, Afin, xs, stats,
                       W11, W12, W21, W22, Wtr, Wse, BT1, BT2, BT3, BT4, BT5);
    hipLaunchKernelGGL(mlp_fused_k, dim3(1284), dim3(256), 0, stream,
                       xs, BT1, b11, BT2, b12, BT3, b21, BT4, b22, Afin);
    hipLaunchKernelGGL(head_gemm_k, dim3(984), dim3(256), 0, stream,
                       Afin, BT5, out, btr, bse, rvw, rvb, stats);
}

// Round 9
// 424.602 us; speedup vs baseline: 1.1642x; 1.1642x over previous
//
#include <hip/hip_runtime.h>
#include <math.h>

// Problem constants
#define BB   128
#define LL   512
#define CC   321
#define PREDD 336
// Seasonal MLP: rows = B*C*S = 164352, dims 128 -> 512 -> 128 (x2 blocks)

using bf16x8  = __attribute__((ext_vector_type(8))) __bf16;
using floatx4 = __attribute__((ext_vector_type(4))) float;
using uintx4  = __attribute__((ext_vector_type(4))) unsigned int;
typedef unsigned short u16;
typedef unsigned int u32;

#define MFMA16(a,b,c) __builtin_amdgcn_mfma_f32_16x16x32_bf16(a,b,c,0,0,0)

__device__ __forceinline__ u16 f2bf(float f){
    union { float f; unsigned u; } v; v.f = f;
    unsigned r = v.u + 0x7FFFu + ((v.u >> 16) & 1u);   // RNE
    return (u16)(r >> 16);
}

// packed f32x2 -> bf16x2 (RNE), 1 instr / 2 elements
__device__ __forceinline__ u32 cvtpk(float a, float b){
    u32 r;
    asm("v_cvt_pk_bf16_f32 %0, %1, %2" : "=v"(r) : "v"(a), "v"(b));
    return r;
}

// tanh-GELU via exp2: max |err| vs exact erf-GELU ~3e-4 << bf16 rounding.
// R6 evidence: per-element form beats batched-rcp (latency-chain bound kernel).
__device__ __forceinline__ float fgelu(float x){
    float u = x*(0.7978845608f + 0.035677408f*x*x);
    float a = fminf(u*2.8853900818f, 80.f);       // 2*log2(e)*u, clamp vs inf/inf
    float t = __builtin_amdgcn_exp2f(a);          // v_exp_f32
    return x*t*__builtin_amdgcn_rcpf(1.f + t);
}

// XOR-segment swizzle (16B segs): s' = (s&8)|((s^r)&7) -- self-inverse.
__device__ __forceinline__ int swz64 (int r, int s){ return r*64  + (((s ^ r) & 7) << 3); }

// async global->LDS DMA, 16B per lane; LDS dest = uniform base + lane*16.
__device__ __forceinline__ void dma16(const u16* g, const u16* l){
    __builtin_amdgcn_global_load_lds(
        (const __attribute__((address_space(1))) u32*)g,
        (__attribute__((address_space(3))) u32*)l, 16, 0, 0);
}

// ---------------- merged prep + decomp (R8 structure, neutral-kept) -----------------------
// Blocks [0,2688): fused RevIN stats + moving-avg decomposition (XCD-remapped).
// Blocks [2688,4224): weight prep fp32->bf16 pre-transposed.
#define XT(t,c) xt[((t)<<4) + (((t)>>5)<<1) + (c)]
__global__ __launch_bounds__(256) void dp_k(
    const float* __restrict__ x, const float* __restrict__ rw, const float* __restrict__ rb,
    u16* __restrict__ Afin, u16* __restrict__ xs, float2* __restrict__ stats,
    const float* __restrict__ W11, const float* __restrict__ W12,
    const float* __restrict__ W21, const float* __restrict__ W22,
    const float* __restrict__ Wtr, const float* __restrict__ Wse,
    u16* __restrict__ BT1, u16* __restrict__ BT2,
    u16* __restrict__ BT3, u16* __restrict__ BT4,
    u16* __restrict__ BT5)
{
    if (blockIdx.x >= 2688){
        // ---- prep body ----
        int idx = (blockIdx.x - 2688) * 256 + threadIdx.x;
        if (idx < 65536){
            int h = idx >> 7;                      // BT1/BT3: [512][128] = W11^T / W21^T (sigma rows)
            int k = idx & 127;
            int hp = (h & ~31) | (((h >> 2) & 3)*8 + ((h >> 4) & 1)*4 + (h & 3));
            BT1[idx] = f2bf(W11[k*512 + hp]);
            BT3[idx] = f2bf(W21[k*512 + hp]);
            int n = idx >> 9, k2 = idx & 511;      // BT2/BT4: [128][512] = W12^T / W22^T
            int np = ((n >> 5) & 3)*32 + ((n >> 2) & 3)*8 + ((n >> 4) & 1)*4 + (n & 3);
            BT2[idx] = f2bf(W12[k2*128 + np]);     // rows n~-permuted
            BT4[idx] = f2bf(W22[k2*128 + n]);      // identity
        }
        if (idx < 393216){
            // BT5: [384][1024]; k<512 -> W_tr rows; k>=512 -> W_se rows permuted to (s,n)-major
            int p = idx >> 10, k = idx & 1023;
            float v = 0.f;
            if (p < PREDD){
                if (k < 512) v = Wtr[k*PREDD + p];
                else { int kk = k - 512; int s = kk >> 7; int n = kk & 127; v = Wse[(4*n + s)*PREDD + p]; }
            }
            BT5[idx] = f2bf(v);
        }
        return;
    }

    // ---- decomp body ----
    __shared__ float xt[8240];
    __shared__ float red[2][16][16];
    __shared__ float sh_m[16], sh_istd[16];
    int b = blockIdx.x & 127, ct = blockIdx.x >> 7;   // XCD co-location remap
    int tid = threadIdx.x;

    int cl = tid & 15, lp = tid >> 4;
    int c = ct*16 + cl;
    bool valid = c < CC;
    const float* xb = x + (size_t)b*LL*CC;
    float s = 0.f, q = 0.f;
    for (int i = 0; i < 32; ++i){
        int t = lp + 16*i;
        float v = valid ? xb[(size_t)t*CC + c] : 0.f;
        XT(t, cl) = v;
        s += v; q += v*v;
    }
    red[0][lp][cl] = s; red[1][lp][cl] = q;
    __syncthreads();
    if (tid < 16){
        float ss = 0.f, qq = 0.f;
        for (int j = 0; j < 16; ++j){ ss += red[0][j][tid]; qq += red[1][j][tid]; }
        float m  = ss * (1.f/512.f);
        float var = qq * (1.f/512.f) - m*m;
        float sd = sqrtf(var + 1e-5f);
        sh_m[tid] = m; sh_istd[tid] = 1.f/sd;
        int cc = ct*16 + tid;
        if (cc < CC) stats[(size_t)b*CC + cc] = make_float2(m, sd);
    }
    __syncthreads();

    int ch = tid >> 4, tp = tid & 15;
    int c2 = ct*16 + ch;
    if (c2 >= CC) return;
    float m = sh_m[ch], istd = sh_istd[ch];
    float w = rw[c2] * istd, bbv = rb[c2];
    size_t bc = (size_t)b*CC + c2;
    u16* tr  = Afin + bc*1024;
    u16* xsr = xs   + bc*512;
    int t0 = tp*32;

    float win = 0.f;
#pragma unroll
    for (int d = -12; d <= 12; ++d){
        int u = t0 + d; u = u < 0 ? 0 : (u > 511 ? 511 : u);
        win += XT(u, ch);
    }
    u16 trbuf[8];
    u16 xsbuf[4][8];
#pragma unroll
    for (int i = 0; i < 32; ++i){
        int t = t0 + i;
        float Ax = win * (1.f/25.f);
        float xv = XT(t, ch);
        trbuf[i & 7] = f2bf((Ax - m)*w + bbv);
        xsbuf[i & 3][i >> 2] = f2bf((xv - Ax)*w);
        if ((i & 7) == 7)
            *(uintx4*)(tr + t0 + (i & ~7)) = *(const uintx4*)trbuf;
        int uo = t - 12; uo = uo < 0 ? 0 : uo;
        int un = t + 13; un = un > 511 ? 511 : un;
        win += XT(un, ch) - XT(uo, ch);
    }
#pragma unroll
    for (int s4 = 0; s4 < 4; ++s4)
        *(uintx4*)(xsr + s4*128 + tp*8) = *(const uintx4*)xsbuf[s4];
}

// ---------------- fused 2-block MLP (R7 body verbatim, (256,3) -- R8's (256,4) spilled) ---
__global__ __launch_bounds__(256, 3) void mlp_fused_k(
    const u16* __restrict__ xs,
    const u16* __restrict__ BT1, const float* __restrict__ b11,
    const u16* __restrict__ BT2, const float* __restrict__ b12,
    const u16* __restrict__ BT3, const float* __restrict__ b21,
    const u16* __restrict__ BT4, const float* __restrict__ b22,
    u16* __restrict__ Afin)
{
    __shared__ u16 lds[16384];   // 32 KB: slot g&1: [0,4096) W1c[32][128]swz128, [4096,8192) W2c[128][32]swz
    const int tid  = threadIdx.x;
    const int lane = tid & 63;
    const int wv   = tid >> 6;
    const int quad = lane >> 4, cl = lane & 15;
    const int wrow = blockIdx.x * 128 + wv*32;       // wave's 32 rows

    // per-thread DMA offsets (constant across g)
    const int qq0 = tid, qq1 = tid + 256;
    const int rA0 = qq0 >> 4, spA0 = qq0 & 15;
    const int rA1 = qq1 >> 4, spA1 = qq1 & 15;
    const int offA0 = rA0*128 + (((spA0 & 8) | ((spA0 ^ rA0) & 7)) << 3);
    const int offA1 = rA1*128 + (((spA1 & 8) | ((spA1 ^ rA1) & 7)) << 3);
    const int rB0 = qq0 >> 2, spB0 = qq0 & 3;
    const int rB1 = qq1 >> 2, spB1 = qq1 & 3;
    const int offB0 = rB0*512 + ((spB0 ^ ((rB0 >> 1) & 3)) << 3);
    const int offB1 = rB1*512 + ((spB1 ^ ((rB1 >> 1) & 3)) << 3);

#define STAGE(dst, w1src, w2src, G)                                          \
    dma16((w1src) + (G)*4096 + offA0, lds + (dst) + qq0*8);                  \
    dma16((w1src) + (G)*4096 + offA1, lds + (dst) + qq1*8);                  \
    dma16((w2src) + (G)*32  + offB0, lds + (dst) + 4096 + qq0*8);            \
    dma16((w2src) + (G)*32  + offB1, lds + (dst) + 4096 + qq1*8);

    // chunk 0 -> slot 0
    STAGE(0, BT1, BT2, 0)

    // x fragments from global (L2/L3-warm from decomp); GEMM1 B-operand. Once per wave.
    bf16x8 xfrag[2][4];
#pragma unroll
    for (int mt = 0; mt < 2; ++mt)
#pragma unroll
        for (int ks = 0; ks < 4; ++ks)
            xfrag[mt][ks] = *(const bf16x8*)(xs + (size_t)(wrow + mt*16 + cl)*128 + ks*32 + quad*8);

    floatx4 Yacc[16];
#pragma unroll
    for (int i = 0; i < 16; ++i) Yacc[i] = (floatx4){0.f,0.f,0.f,0.f};

    __syncthreads();                                 // chunk 0 landed

    const int w2rd = (quad ^ ((cl >> 1) & 3)) << 3;  // W2c read seg offset (u16)

    for (int g = 0; g < 32; ++g){
        const int cur = (g & 1) ? 8192 : 0;
        if (g < 31){                                 // DMA chunk g+1 (lands during this chunk)
            const int nxt = 8192 - cur;
            const u16* w1s = ((g+1) & 16) ? BT3 : BT1;
            const u16* w2s = ((g+1) & 16) ? BT4 : BT2;
            const int hn = (g+1) & 15;
            STAGE(nxt, w1s, w2s, hn)
        }
        const float* ba = (g & 16) ? b21 : b11;
        const int hc = g & 15;

        // GEMM1: hacc[f][mt] = W1c x xfrag  (Ht tiles; h-slot = 4*quad+i, m = cl)
        floatx4 hacc[2][2];
        hacc[0][0] = hacc[0][1] = hacc[1][0] = hacc[1][1] = (floatx4){0.f,0.f,0.f,0.f};
#pragma unroll
        for (int ks = 0; ks < 4; ++ks){
            const int sg = ks*4 + quad;
            const int s0 = ((sg & 8) | ((sg ^ cl) & 7)) << 3;
            bf16x8 wf0 = *(const bf16x8*)(lds + cur + cl*128 + s0);
            bf16x8 wf1 = *(const bf16x8*)(lds + cur + (16 + cl)*128 + s0);
#pragma unroll
            for (int mt = 0; mt < 2; ++mt){
                hacc[0][mt] = MFMA16(wf0, xfrag[mt][ks], hacc[0][mt]);
                hacc[1][mt] = MFMA16(wf1, xfrag[mt][ks], hacc[1][mt]);
            }
        }

        // bias + GELU + pack: lane's 8 values ARE its B-fragment (sigma permutation)
        const float4 bA = *(const float4*)(ba + hc*32 + quad*8);
        const float4 bB = *(const float4*)(ba + hc*32 + quad*8 + 4);
        bf16x8 a2[2];
#pragma unroll
        for (int mt = 0; mt < 2; ++mt){
            union { bf16x8 v; u32 w[4]; } u;
            u.w[0] = cvtpk(fgelu(hacc[0][mt][0] + bA.x), fgelu(hacc[0][mt][1] + bA.y));
            u.w[1] = cvtpk(fgelu(hacc[0][mt][2] + bA.z), fgelu(hacc[0][mt][3] + bA.w));
            u.w[2] = cvtpk(fgelu(hacc[1][mt][0] + bB.x), fgelu(hacc[1][mt][1] + bB.y));
            u.w[3] = cvtpk(fgelu(hacc[1][mt][2] + bB.z), fgelu(hacc[1][mt][3] + bB.w));
            a2[mt] = u.v;
        }

        // GEMM2: Yacc (Y^T) += W2c x a2   (n-slot tiles nt2, m = cl)
#pragma unroll
        for (int nt2 = 0; nt2 < 8; ++nt2){
            bf16x8 b2 = *(const bf16x8*)(lds + cur + 4096 + (nt2*16 + cl)*32 + w2rd);
#pragma unroll
            for (int mt = 0; mt < 2; ++mt)
                Yacc[mt*8 + nt2] = MFMA16(b2, a2[mt], Yacc[mt*8 + nt2]);
        }
        __syncthreads();                             // slot reads done + DMA g+1 drained

        if (g == 15){
            // mlp0 -> mlp1 handoff: h1 = Y + b12, register-only (n~ permutation)
#pragma unroll
            for (int ks = 0; ks < 4; ++ks){
                const float4 cA = *(const float4*)(b12 + ks*32 + quad*8);
                const float4 cB = *(const float4*)(b12 + ks*32 + quad*8 + 4);
#pragma unroll
                for (int mt = 0; mt < 2; ++mt){
                    floatx4 y0 = Yacc[mt*8 + 2*ks];
                    floatx4 y1 = Yacc[mt*8 + 2*ks + 1];
                    union { bf16x8 v; u32 w[4]; } u;
                    u.w[0] = cvtpk(y0[0] + cA.x, y0[1] + cA.y);
                    u.w[1] = cvtpk(y0[2] + cA.z, y0[3] + cA.w);
                    u.w[2] = cvtpk(y1[0] + cB.x, y1[1] + cB.y);
                    u.w[3] = cvtpk(y1[2] + cB.z, y1[3] + cB.w);
                    xfrag[mt][ks] = u.v;
                }
            }
#pragma unroll
            for (int i = 0; i < 16; ++i) Yacc[i] = (floatx4){0.f,0.f,0.f,0.f};
        }
    }
#undef STAGE

    // epilogue: h2 + b22 -> Afin[:, 512 + s*128 + n]; 8B packed stores
#pragma unroll
    for (int mt = 0; mt < 2; ++mt){
        const int gr = wrow + mt*16 + cl;
        u16* dst = Afin + (size_t)(gr >> 2)*1024 + 512 + (size_t)(gr & 3)*128 + quad*4;
#pragma unroll
        for (int nt2 = 0; nt2 < 8; ++nt2){
            const float4 cB = *(const float4*)(b22 + nt2*16 + quad*4);
            floatx4 v = Yacc[mt*8 + nt2];
            union { unsigned long long d; u32 w[2]; } u;
            u.w[0] = cvtpk(v[0] + cB.x, v[1] + cB.y);
            u.w[1] = cvtpk(v[2] + cB.z, v[3] + cB.w);
            *(unsigned long long*)(dst + nt2*16) = u.d;
        }
    }
}

// ---------------- final fused-head GEMM (R9: swapped MFMA operands -> coalesced stores) ---
// Swapping A/B transposes the C fragment: cl now indexes the output's c-direction
// (contiguous), quad*4+i indexes p. Validated layout precedent: mlp GEMM1 uses the same
// swapped form ("m = cl"). Store instrs become 4 x 64B segments (was 64 x 4B scatters);
// per-c RevIN math (div/mod/rb/rw/stats) hoists from 64x to 2x per wave.
__global__ __launch_bounds__(256, 2) void head_gemm_k(
    const u16* __restrict__ A, const u16* __restrict__ BT,
    float* __restrict__ Cf,
    const float* __restrict__ bias, const float* __restrict__ bias2,
    const float* __restrict__ rw, const float* __restrict__ rb,
    const float2* __restrict__ stats)
{
    __shared__ u16 lds[32768];    // A slices @0,@8192 ; B slices @16384,@24576
    const int id = blockIdx.x;
    const int xcd = id & 7, slot = id >> 3;
    const int g8 = slot / 3, j = slot - g8*3;
    const int by = xcd + 8*g8;
    if (by >= 321) return;
    const int row0 = by * 128, col0 = j * 128;

    const int tid = threadIdx.x;
    const int lane = tid & 63;
    const int wv = tid >> 6;
    const int wm = wv & 1, wn = wv >> 1;
    const int quad = lane >> 4, cl = lane & 15;

    const int qbase = wv*4*64 + lane;

#pragma unroll
    for (int i = 0; i < 4; ++i){
        int qq = qbase + i*64;
        int r = qq >> 3, p = qq & 7; int s = (p ^ r) & 7;
        dma16(A  + (size_t)(row0 + r)*1024 + s*8, lds + qq*8);
        dma16(BT + (size_t)(col0 + r)*1024 + s*8, lds + 16384 + qq*8);
    }
    __syncthreads();

    floatx4 acc[16];
#pragma unroll
    for (int i = 0; i < 16; ++i) acc[i] = (floatx4){0.f,0.f,0.f,0.f};

    for (int it = 0; it < 16; ++it){
        const int cur = (it & 1) * 8192;
        if (it < 15){
            const int nxt = ((it+1) & 1) * 8192;
            const int k0 = (it+1) * 64;
#pragma unroll
            for (int i = 0; i < 4; ++i){
                int qq = qbase + i*64;
                int r = qq >> 3, p = qq & 7; int s = (p ^ r) & 7;
                dma16(A  + (size_t)(row0 + r)*1024 + k0 + s*8, lds + nxt + qq*8);
                dma16(BT + (size_t)(col0 + r)*1024 + k0 + s*8, lds + 16384 + nxt + qq*8);
            }
        }
#pragma unroll
        for (int kk = 0; kk < 2; ++kk){
            bf16x8 af[4], bfr[4];
#pragma unroll
            for (int mt = 0; mt < 4; ++mt) af[mt]  = *(const bf16x8*)(lds + cur + swz64(wm*64 + mt*16 + cl, kk*4 + quad));
#pragma unroll
            for (int nt = 0; nt < 4; ++nt) bfr[nt] = *(const bf16x8*)(lds + 16384 + cur + swz64(wn*64 + nt*16 + cl, kk*4 + quad));
#pragma unroll
            for (int mt = 0; mt < 4; ++mt)
#pragma unroll
                for (int nt = 0; nt < 4; ++nt)
                    acc[mt*4+nt] = MFMA16(bfr[nt], af[mt], acc[mt*4+nt]);   // SWAPPED: C^T frag
        }
        __syncthreads();
    }

    // epilogue: cl -> gr (c-contiguous), quad*4+i -> gc (p). Per-lane RevIN hoisted per mt.
#pragma unroll
    for (int mt = 0; mt < 4; ++mt){
        const int gr = row0 + wm*64 + mt*16 + cl;     // lane's output row (b,c)
        const int bv2 = gr / CC;
        const int c   = gr - bv2*CC;
        const float rbc = rb[c];
        const float rwc = rw[c] + 1e-10f;
        const float2 st = stats[gr];
        float* cbase = Cf + (size_t)bv2*(PREDD*CC) + c;
#pragma unroll
        for (int nt = 0; nt < 4; ++nt){
            floatx4 v = acc[mt*4+nt];
#pragma unroll
            for (int i = 0; i < 4; ++i){
                const int p = col0 + wn*64 + nt*16 + quad*4 + i;
                if (p >= PREDD) continue;
                float val = v[i] + bias[p] + bias2[p];
                val = (val - rbc) / rwc;
                val = val*st.y + st.x;
                cbase[(size_t)p*CC] = val;
            }
        }
    }
}

extern "C" void kernel_launch(void* const* d_in, const int* in_sizes, int n_in,
                              void* d_out, int out_size, void* d_ws, size_t ws_size,
                              hipStream_t stream)
{
    const float* x   = (const float*)d_in[0];
    const float* rvw = (const float*)d_in[1];
    const float* rvb = (const float*)d_in[2];
    const float* W11 = (const float*)d_in[3];
    const float* b11 = (const float*)d_in[4];
    const float* W12 = (const float*)d_in[5];
    const float* b12 = (const float*)d_in[6];
    const float* W21 = (const float*)d_in[7];
    const float* b21 = (const float*)d_in[8];
    const float* W22 = (const float*)d_in[9];
    const float* b22 = (const float*)d_in[10];
    const float* Wtr = (const float*)d_in[11];
    const float* btr = (const float*)d_in[12];
    const float* Wse = (const float*)d_in[13];
    const float* bse = (const float*)d_in[14];
    float* out = (float*)d_out;

    char* ws = (char*)d_ws;
    u16* BT1 = (u16*)(ws + 0);            //  512x128 bf16 (sigma-permuted rows)
    u16* BT2 = (u16*)(ws + 131072);       //  128x512 (n~-permuted rows)
    u16* BT3 = (u16*)(ws + 262144);       //  512x128 (sigma-permuted rows)
    u16* BT4 = (u16*)(ws + 393216);       //  128x512 (identity)
    u16* BT5 = (u16*)(ws + 524288);       //  384x1024
    float2* stats = (float2*)(ws + 1310720);      // 41088 x {mean,std}
    u16* Afin = (u16*)(ws + 1639424);     // concat-A [41088][1024]: trend | sea
    u16* xs   = (u16*)(ws + 85787648);    // [164352][128] split seasonal

    hipLaunchKernelGGL(dp_k, dim3(4224), dim3(256), 0, stream,
                       x, rvw, rvb, Afin, xs, stats,
                       W11, W12, W21, W22, Wtr, Wse, BT1, BT2, BT3, BT4, BT5);
    hipLaunchKernelGGL(mlp_fused_k, dim3(1284), dim3(256), 0, stream,
                       xs, BT1, b11, BT2, b12, BT3, b21, BT4, b22, Afin);
    hipLaunchKernelGGL(head_gemm_k, dim3(984), dim3(256), 0, stream,
                       Afin, BT5, out, btr, bse, rvw, rvb, stats);
}